// Round 8
// baseline (531.801 us; speedup 1.0000x reference)
//
#include <hip/hip_runtime.h>

#define BINS 10
#define TPB  256
#define NBLK 2048

// ws layout (21 dwords): unsigned ticket; float bsum[BINS]; int bcnt[BINS]
// (harness poisons ws to 0xAA before every launch -> zero-kernel inits it)

__global__ __launch_bounds__(64) void ghmc_zero(unsigned* ws) {
    int i = threadIdx.x;
    if (i < 1 + 2 * BINS) ws[i] = 0u;
}

// Per-element update, all VGPR-local (lessons: r3 = per-element LDS atomics are
// a ~137us floor; r5 = min-waves launch_bounds forces scratch spill; r6 = per-
// element __ballot is a VALU->SALU dependency disaster, 3.6x regression).
// Algebra: t in {0,1} -> y = p*(1-2t); bce = softplus(y); bin via y >= logit(b/10).
// Cumulative sums S_b / counts cnt_b; per-bin recovered as adjacent differences.
// Invalid (w==0): ye=-60 -> below all thresholds, softplus(-60)==0.0f exactly.
// Valid-count accumulated as float sum of w itself (w in {0,1} exactly, <=41/lane).
#define GHMC_ELEM(pk, tk, wk)                                                 \
    do {                                                                      \
        float tm_ = __builtin_fmaf((tk), -2.0f, 1.0f);  /* {1,-1} exact */    \
        float y_  = tm_ * (pk);                                               \
        bool  v_  = ((wk) > 0.0f);                                            \
        float ye_ = v_ ? y_ : -60.0f;                                         \
        float e_  = __expf(-__builtin_fabsf(ye_));      /* (0,1] */           \
        float onep_ = 1.0f + e_;                        /* (1,2]: log exact */\
        float bce_  = __builtin_fmaf(0.69314718055994530942f,                 \
                                     __log2f(onep_),                          \
                                     __builtin_fmaxf(ye_, 0.0f));             \
        S[0] += bce_;                                                         \
        c0f  += (wk);                                                         \
        _Pragma("unroll")                                                     \
        for (int b_ = 1; b_ < BINS; ++b_) {                                   \
            bool ge_ = (ye_ >= kL[b_ - 1]);                                   \
            S[b_]       += ge_ ? bce_ : 0.0f;                                 \
            cnt[b_ - 1] += ge_ ? 1 : 0;  /* addc off live vcc */              \
        }                                                                     \
    } while (0)

#define GHMC_ELEM4(P, T, W_)                                                  \
    do {                                                                      \
        GHMC_ELEM((P).x, (T).x, (W_).x);                                      \
        GHMC_ELEM((P).y, (T).y, (W_).y);                                      \
        GHMC_ELEM((P).z, (T).z, (W_).z);                                      \
        GHMC_ELEM((P).w, (T).w, (W_).w);                                      \
    } while (0)

__global__ __launch_bounds__(256) void ghmc_main(
    const float* __restrict__ pred, const float* __restrict__ targ,
    const float* __restrict__ lw,
    unsigned* __restrict__ ticket, float* __restrict__ bsum,
    int* __restrict__ bcnt, float* __restrict__ out, int n) {

    // logit(b/10), b=1..9
    const float kL[9] = { -2.1972246f, -1.3862944f, -0.84729786f, -0.40546511f,
                          0.0f, 0.40546511f, 0.84729786f, 1.3862944f, 2.1972246f };

    float S[BINS];      // per-lane cumulative sums
    int   cnt[BINS - 1];// per-lane cumulative counts, bins 1..9
    float c0f = 0.0f;   // per-lane valid count (exact float sum of w)
#pragma unroll
    for (int b = 0; b < BINS; ++b) S[b] = 0.0f;
#pragma unroll
    for (int b = 0; b < BINS - 1; ++b) cnt[b] = 0;

    const int nvec = n >> 2;
    // contiguous chunk per block (2048 blocks -> exactly 2560 vec4 = 10/thread)
    const int start = (int)(((long long)nvec * blockIdx.x) / gridDim.x);
    const int end   = (int)(((long long)nvec * (blockIdx.x + 1)) / gridDim.x);
    const int cnt4  = end - start;

    const float4* p4 = (const float4*)pred;
    const float4* t4 = (const float4*)targ;
    const float4* w4 = (const float4*)lw;

    if ((cnt4 & (TPB - 1)) == 0 && cnt4 >= 2 * TPB) {
        // ---- uniform-trip hot path: no guards, depth-2 software pipeline ----
        const int iters = cnt4 >> 8;          // cnt4 / TPB, >= 2
        const int i0    = start + (int)threadIdx.x;
        float4 p0 = p4[i0],       t0 = t4[i0],       w0 = w4[i0];
        float4 p1 = p4[i0 + TPB], t1 = t4[i0 + TPB], w1 = w4[i0 + TPB];
        for (int k = 2; k < iters; ++k) {
            const int j = i0 + k * TPB;
            float4 pn = p4[j], tn = t4[j], wn = w4[j];
            GHMC_ELEM4(p0, t0, w0);
            p0 = p1; t0 = t1; w0 = w1;
            p1 = pn; t1 = tn; w1 = wn;
        }
        GHMC_ELEM4(p0, t0, w0);
        GHMC_ELEM4(p1, t1, w1);
    } else {
        // ---- generic fallback (guarded, depth-1) ----
        for (int i = start + (int)threadIdx.x; i < end; i += TPB) {
            float4 p = p4[i], t = t4[i], w = w4[i];
            GHMC_ELEM4(p, t, w);
        }
    }

    // scalar tail (n not divisible by 4)
    {
        int rem  = n & 3;
        int gtid = blockIdx.x * TPB + (int)threadIdx.x;
        if (gtid < rem) {
            int idx = (nvec << 2) + gtid;
            float pk = pred[idx], tk = targ[idx], wk = lw[idx];
            GHMC_ELEM(pk, tk, wk);
        }
    }

    // per-lane cumulative -> per-bin
    float lsum[BINS];
    int   lcnt[BINS];
    {
        int Cc[BINS];
        Cc[0] = (int)c0f;
#pragma unroll
        for (int b = 1; b < BINS; ++b) Cc[b] = cnt[b - 1];
#pragma unroll
        for (int b = 0; b < BINS - 1; ++b) {
            lsum[b] = S[b] - S[b + 1];
            lcnt[b] = Cc[b] - Cc[b + 1];
        }
        lsum[BINS - 1] = S[BINS - 1];
        lcnt[BINS - 1] = Cc[BINS - 1];
    }

    // ---- wave butterfly, block LDS, one global atomic per bin ----
    __shared__ float s_bsum[BINS];
    __shared__ int   s_bcnt[BINS];
    __shared__ int   s_last;
    if (threadIdx.x < BINS) { s_bsum[threadIdx.x] = 0.0f; s_bcnt[threadIdx.x] = 0; }
    __syncthreads();

    const int lane = threadIdx.x & 63;
#pragma unroll
    for (int b = 0; b < BINS; ++b) {
        float s = lsum[b];
        int   c = lcnt[b];
#pragma unroll
        for (int off = 32; off > 0; off >>= 1) {
            s += __shfl_xor(s, off, 64);
            c += __shfl_xor(c, off, 64);
        }
        if (lane == 0 && c != 0) {
            atomicAdd(&s_bsum[b], s);
            atomicAdd(&s_bcnt[b], c);
        }
    }
    __syncthreads();

    if (threadIdx.x < BINS) {
        float s = s_bsum[threadIdx.x];
        int   c = s_bcnt[threadIdx.x];
        if (c != 0) {
            atomicAdd(&bsum[threadIdx.x], s);   // device-scope by default
            atomicAdd(&bcnt[threadIdx.x], c);
        }
    }
    __threadfence();      // release: this block's global atomics visible
    __syncthreads();      // whole block done + fenced

    // ---- last-block-done: finalize fused into main ----
    if (threadIdx.x == 0) {
        unsigned old = atomicAdd(ticket, 1u);
        s_last = (old == (unsigned)(gridDim.x - 1)) ? 1 : 0;
    }
    __syncthreads();

    if (s_last && threadIdx.x == 0) {
        __threadfence();  // acquire: all other blocks' atomics visible
        float acc = 0.0f;
        int nb = 0;
#pragma unroll
        for (int b = 0; b < BINS; ++b) {
            int c = atomicAdd(&bcnt[b], 0);           // device-coherent read
            if (c > 0) {
                float s = atomicAdd(&bsum[b], 0.0f);  // device-coherent read
                nb += 1;
                acc += s / (float)c;
            }
        }
        out[0] = (nb > 0) ? (acc / (float)nb) : 0.0f;  // LOSS_WEIGHT = 1
    }
}

extern "C" void kernel_launch(void* const* d_in, const int* in_sizes, int n_in,
                              void* d_out, int out_size, void* d_ws, size_t ws_size,
                              hipStream_t stream) {
    const float* pred = (const float*)d_in[0];
    const float* targ = (const float*)d_in[1];
    const float* lw   = (const float*)d_in[2];
    float* out = (float*)d_out;
    const int n = in_sizes[0];   // 262144*80 = 20,971,520

    unsigned* ticket = (unsigned*)d_ws;
    float*    bsum   = (float*)((char*)d_ws + 4);
    int*      bcnt   = (int*)((char*)d_ws + 4 + BINS * sizeof(float));

    ghmc_zero<<<1, 64, 0, stream>>>((unsigned*)d_ws);

    ghmc_main<<<NBLK, TPB, 0, stream>>>(pred, targ, lw,
                                        ticket, bsum, bcnt, out, n);
}